// Round 1
// 180.400 us; speedup vs baseline: 1.0062x; 1.0062x over previous
//
#include <hip/hip_runtime.h>
#include <cstdint>
#include <cstddef>

#define B_  16
#define N_  512
#define D_  256
#define H_  8
#define DK_ 32
// Round 9: occupancy + latency-overlap rework.
//  1) fused_pre grid 2112:
//     [0,512):    ST-build blocks (dist/adj softmax+blend -> g_ST bf16, streaming,
//                 co-scheduled with MFMA GEMM blocks = complementary pipes)
//     [512,2048): QKV MFMA GEMMs (V stored tile-interleaved for coalesced PV reads)
//     [2048,2112): Wo fp32->bf16, tiled [k>>5][n][k&31] for coalesced Phase-C reads
//  2) attn: k-loop chunked 512 -> 4x128 with DEFERRED softmax normalization:
//     acc regs 128 -> 32, total alloc <=128 (launch_bounds 512,4) -> 2 blocks/CU
//     (was 1 block/CU: 88 VGPR + ~128 AGPR acc = ~216/wave, Occupancy 19%).
//     ST staged once per block from g_ST (16KB, L3-hot, shared by 8 heads).
//     oA (attention PV, scaled by 0.3/lsum at end) + oS (ST PV) accumulated
//     separately; per-lane denominator redistributed with one __shfl.

#define QKV_ELEMS 2097152   // B*N*D

__device__ __align__(16) unsigned short g_Qb[QKV_ELEMS];       // [B,H,N,DK] bf16
__device__ __align__(16) unsigned short g_Kb[QKV_ELEMS];       // [B,H,N,DK] bf16
__device__ __align__(16) unsigned short g_VT[QKV_ELEMS];       // [B,H,tokblk16,DK,tok32] bf16
__device__ __align__(16) unsigned short g_WoB[D_*D_];          // Wo bf16 [k>>5][n][k&31]
__device__ __align__(16) unsigned short g_ST[B_*N_*N_];        // blended dist/adj bf16 [b][q][k]

typedef short v8s __attribute__((ext_vector_type(8)));
typedef float v4f __attribute__((ext_vector_type(4)));

__device__ __forceinline__ unsigned short f2b(float f){
  unsigned int x;
  __builtin_memcpy(&x, &f, 4);
  x = x + 0x7FFFu + ((x >> 16) & 1u);   // round-to-nearest-even
  return (unsigned short)(x >> 16);
}
__device__ __forceinline__ v8s pack8(const float4 a, const float4 b){
  v8s o;
  o[0]=(short)f2b(a.x); o[1]=(short)f2b(a.y); o[2]=(short)f2b(a.z); o[3]=(short)f2b(a.w);
  o[4]=(short)f2b(b.x); o[5]=(short)f2b(b.y); o[6]=(short)f2b(b.z); o[7]=(short)f2b(b.w);
  return o;
}

// ---------------------------------------------------------------------------
// Dispatch 1.
// ---------------------------------------------------------------------------
__global__ __launch_bounds__(256) void fused_pre(
    const float* __restrict__ query, const float* __restrict__ key_,
    const float* __restrict__ value,
    const float* __restrict__ Wq, const float* __restrict__ bq,
    const float* __restrict__ Wk, const float* __restrict__ bk,
    const float* __restrict__ Wv, const float* __restrict__ bv,
    const float* __restrict__ Wo,
    const float* __restrict__ dist, const float* __restrict__ adjm,
    const int* __restrict__ mask)
{
  __shared__ unsigned short Wl[64*264];   // 33.8 KB
  const int bid = blockIdx.x;
  const int t   = threadIdx.x;

  if (bid < 512){     // ---- ST build: (b,qt), 16 rows x 512 k, bf16 out ----
    const int b   = bid & 15;
    const int qt  = bid >> 4;
    const int row = t >> 4;           // 0..15
    const int seg = t & 15;           // 32 k each, contiguous
    const size_t roff = ((size_t)(b*N_ + qt*16 + row))*N_ + seg*32;
    const float* dp = dist + roff;
    const float* ap = adjm + roff;
    const int*   mp = mask + b*N_ + seg*32;
    float ev[32], av[32];
    float lz = 0.f, la = 0.f;
    #pragma unroll
    for (int c = 0; c < 8; ++c){
      const float4 d4 = *reinterpret_cast<const float4*>(dp + c*4);
      const float4 a4 = *reinterpret_cast<const float4*>(ap + c*4);
      const int4   m4 = *reinterpret_cast<const int4*>(mp + c*4);
      ev[c*4+0] = m4.x ? __expf(-d4.x) : 0.f;   // -dist in [-1,0]: exp-safe
      ev[c*4+1] = m4.y ? __expf(-d4.y) : 0.f;
      ev[c*4+2] = m4.z ? __expf(-d4.z) : 0.f;
      ev[c*4+3] = m4.w ? __expf(-d4.w) : 0.f;
      av[c*4+0] = a4.x; av[c*4+1] = a4.y; av[c*4+2] = a4.z; av[c*4+3] = a4.w;
      lz += ev[c*4+0] + ev[c*4+1] + ev[c*4+2] + ev[c*4+3];
      la += a4.x + a4.y + a4.z + a4.w;
    }
    // reduce across the 16 lanes that share this row (lanes differ in bits 0..3)
    #pragma unroll
    for (int o = 1; o < 16; o <<= 1){
      lz += __shfl_xor(lz, o, 64);
      la += __shfl_xor(la, o, 64);
    }
    const float c0 = (lz > 0.f) ? 0.3f / lz : 0.f;
    const float c1 = 0.4f / (la + 1e-6f);
    unsigned short* dst = g_ST + roff;
    #pragma unroll
    for (int c2 = 0; c2 < 4; ++c2){
      v8s o8;
      #pragma unroll
      for (int i = 0; i < 8; ++i)
        o8[i] = (short)f2b(ev[c2*8+i]*c0 + av[c2*8+i]*c1);
      *reinterpret_cast<v8s*>(dst + c2*8) = o8;
    }
    return;
  }

  if (bid >= 2048){   // ---- Wo fp32 -> bf16, tiled [k>>5][n][k&31] ----
    const int i = ((bid - 2048)*256 + t)*4;
    const float4 u = *reinterpret_cast<const float4*>(Wo + i);
    const int n = i >> 8, k = i & 255;
    ushort4 o4;
    o4.x = f2b(u.x); o4.y = f2b(u.y); o4.z = f2b(u.z); o4.w = f2b(u.w);
    *reinterpret_cast<ushort4*>(g_WoB + (size_t)(k >> 5)*8192 + (size_t)n*32 + (k & 31)) = o4;
    return;
  }

  // ---- QKV GEMM: C[m][n] = sum_k A[m][k]*W[n][k] + b[n], M=8192, N=K=256 ----
  const int gb = bid - 512;
  const int z  = gb >> 9;                 // 0:Q 1:K 2:V
  const int rr = gb & 511;
  const int mt = rr >> 2, nt = rr & 3;    // nt fastest: 4 consecutive blocks share A tile
  const float* Ap = (z==0) ? query : (z==1) ? key_ : value;
  const float* Wp = (z==0) ? Wq : (z==1) ? Wk : Wv;
  const float* bp = (z==0) ? bq : (z==1) ? bk : bv;
  const int w = t >> 6, lane = t & 63, kl = lane & 15, quad = lane >> 4;
  const int m0 = mt*64 + w*16;
  const int n0 = nt*64;

  {   // stage + convert W tile [n0..n0+63][0..255]
    const int row = t >> 2;
    const int ks  = (t & 3) * 64;
    const float* src = Wp + (size_t)(n0+row)*256 + ks;
    unsigned short* dst = Wl + row*264 + ks;
    #pragma unroll
    for (int u = 0; u < 8; ++u){
      const float4 u0 = reinterpret_cast<const float4*>(src)[2*u];
      const float4 u1 = reinterpret_cast<const float4*>(src)[2*u+1];
      *reinterpret_cast<v8s*>(dst + u*8) = pack8(u0, u1);
    }
  }
  __syncthreads();

  v4f acc[4];
  #pragma unroll
  for (int nb = 0; nb < 4; ++nb) acc[nb] = (v4f){0.f,0.f,0.f,0.f};
  const int arow = m0 + kl;

  if (z == 2){
    #pragma unroll
    for (int k0 = 0; k0 < 256; k0 += 32){
      const float* ap = Ap + (size_t)arow*256 + k0 + quad*8;
      const v8s af = pack8(reinterpret_cast<const float4*>(ap)[0],
                           reinterpret_cast<const float4*>(ap)[1]);
      #pragma unroll
      for (int nb = 0; nb < 4; ++nb){
        const v8s wf = *reinterpret_cast<const v8s*>(&Wl[(nb*16+kl)*264 + k0 + quad*8]);
        acc[nb] = __builtin_amdgcn_mfma_f32_16x16x32_bf16(wf, af, acc[nb], 0, 0, 0);
      }
    }
    // D[n][tok]; store tile-interleaved: [bb,h, tokblk, dk, tok&31]
    const int tok = m0 + kl, bb = tok >> 9, nr = tok & 511;
    #pragma unroll
    for (int nb = 0; nb < 4; ++nb)
      #pragma unroll
      for (int r = 0; r < 4; ++r){
        const int n = n0 + nb*16 + quad*4 + r;
        const float v = acc[nb][r] + bp[n];
        g_VT[(((size_t)bb*H_ + (n>>5))*16 + (nr>>5))*1024 + (size_t)(n&31)*32 + (nr&31)] = f2b(v);
      }
  } else {
    #pragma unroll
    for (int k0 = 0; k0 < 256; k0 += 32){
      const float* ap = Ap + (size_t)arow*256 + k0 + quad*8;
      const v8s af = pack8(reinterpret_cast<const float4*>(ap)[0],
                           reinterpret_cast<const float4*>(ap)[1]);
      #pragma unroll
      for (int nb = 0; nb < 4; ++nb){
        const v8s wf = *reinterpret_cast<const v8s*>(&Wl[(nb*16+kl)*264 + k0 + quad*8]);
        acc[nb] = __builtin_amdgcn_mfma_f32_16x16x32_bf16(af, wf, acc[nb], 0, 0, 0);
      }
    }
    unsigned short* dst = z ? g_Kb : g_Qb;
    #pragma unroll
    for (int nb = 0; nb < 4; ++nb){
      const int n = n0 + nb*16 + kl;
      const float bias = bp[n];
      #pragma unroll
      for (int r = 0; r < 4; ++r){
        const int m = m0 + quad*4 + r;
        const float v = acc[nb][r] + bias;
        dst[(((size_t)(m>>9)*H_ + (n>>5))*N_ + (m&511))*DK_ + (n&31)] = f2b(v);
      }
    }
  }
}

// ---------------------------------------------------------------------------
// Dispatch 2: attention. 512 thr = 8 waves = 8 heads; one (b,qtile).
// k chunked 4x128, deferred softmax normalization -> <=128 regs -> 2 blocks/CU.
// ---------------------------------------------------------------------------
__global__ __launch_bounds__(512, 4) void attn_kernel(
    const int* __restrict__ mask, const float* __restrict__ bo,
    float* __restrict__ out)
{
  __shared__ unsigned short STl[16*520];    // 16.6 KB  ST[qrow][k] bf16 (padded)
  __shared__ unsigned short Pl[8*16*40];    // 10.2 KB  per-wave P chunk
  __shared__ unsigned short Xl[16*272];     //  8.7 KB  X[qrow][n] bf16
  const int bid = blockIdx.x;
  const int b  = bid & 15;                  // same-b -> same XCD (K/V L2 reuse)
  const int qt = bid >> 4;
  const int q0 = qt*16;
  const int t  = threadIdx.x;
  const int w  = t >> 6, lane = t & 63;
  const int kl = lane & 15, quad = lane >> 4;

  // ---- stage precomputed ST tile (16KB bf16, L3-hot) into padded LDS ----
  {
    const int row = t >> 5;                 // 16 rows, 32 thr each
    const int c16 = (t & 31) * 16;
    const unsigned short* src = g_ST + ((size_t)(b*N_ + q0 + row))*N_ + c16;
    *reinterpret_cast<v8s*>(&STl[row*520 + c16])     = *reinterpret_cast<const v8s*>(src);
    *reinterpret_cast<v8s*>(&STl[row*520 + c16 + 8]) = *reinterpret_cast<const v8s*>(src + 8);
  }

  const int h = w;
  const size_t bh = (size_t)b*H_ + h;
  const float scale = 0.17677669529663687f;   // 1/sqrt(32)
  const unsigned short* Qp = g_Qb + (bh*N_ + q0)*DK_;
  const unsigned short* Kp = g_Kb + bh*N_*DK_;
  const unsigned short* Vp = g_VT + bh*(size_t)(N_*DK_);
  unsigned short* Plw = Pl + w*640;           // 16x40 per wave
  const int* mrow = mask + b*N_;
  const v8s aq = *reinterpret_cast<const v8s*>(Qp + (size_t)kl*DK_ + quad*8);
  const v4f vz = {0.f, 0.f, 0.f, 0.f};

  v4f oA0 = vz, oA1 = vz;     // attention PV (unnormalized)
  v4f oS0 = vz, oS1 = vz;     // ST PV (pre-scaled)
  float lsum[4] = {0.f, 0.f, 0.f, 0.f};

  __syncthreads();            // STl visible to all waves

  #pragma unroll 1
  for (int ch = 0; ch < 4; ++ch){
    const int k0 = ch*128;
    v4f acc[8];
    #pragma unroll
    for (int kb = 0; kb < 8; ++kb){
      const v8s bk = *reinterpret_cast<const v8s*>(Kp + (size_t)(k0 + kb*16 + kl)*DK_ + quad*8);
      acc[kb] = __builtin_amdgcn_mfma_f32_16x16x32_bf16(aq, bk, vz, 0, 0, 0);
    }
    #pragma unroll
    for (int kb = 0; kb < 8; ++kb){
      const bool valid = (mrow[k0 + kb*16 + kl] != 0);
      #pragma unroll
      for (int r = 0; r < 4; ++r){
        const float e = valid ? __expf(acc[kb][r]*scale) : 0.f;
        acc[kb][r] = e;               // raw exp; normalize at the end
        lsum[r] += e;
      }
    }
    #pragma unroll
    for (int cc = 0; cc < 4; ++cc){
      #pragma unroll
      for (int r = 0; r < 4; ++r){
        Plw[(quad*4 + r)*40 + kl]      = f2b(acc[2*cc    ][r]);
        Plw[(quad*4 + r)*40 + 16 + kl] = f2b(acc[2*cc + 1][r]);
      }
      const int kk = k0 + cc*32;
      // wave-private region: same-wave write->read ordered via lgkmcnt
      const v8s bp  = *reinterpret_cast<const v8s*>(&Plw[kl*40 + quad*8]);
      const v8s bst = *reinterpret_cast<const v8s*>(&STl[kl*520 + kk + quad*8]);
      const v8s av0 = *reinterpret_cast<const v8s*>(Vp + (size_t)(kk + kl)*32 + quad*8);
      const v8s av1 = *reinterpret_cast<const v8s*>(Vp + (size_t)(kk + 16 + kl)*32 + quad*8);
      oA0 = __builtin_amdgcn_mfma_f32_16x16x32_bf16(av0, bp,  oA0, 0, 0, 0);
      oS0 = __builtin_amdgcn_mfma_f32_16x16x32_bf16(av0, bst, oS0, 0, 0, 0);
      oA1 = __builtin_amdgcn_mfma_f32_16x16x32_bf16(av1, bp,  oA1, 0, 0, 0);
      oS1 = __builtin_amdgcn_mfma_f32_16x16x32_bf16(av1, bst, oS1, 0, 0, 0);
    }
  }

  // softmax denominators: lsum[r] = full-row sum for q = quad*4+r
  #pragma unroll
  for (int r = 0; r < 4; ++r)
    #pragma unroll
    for (int o = 1; o < 16; o <<= 1) lsum[r] += __shfl_xor(lsum[r], o, 64);
  // redistribute: this lane's O columns are q = kl; fetch lsum[kl&3] from quad kl>>2
  const float s01 = (kl & 1) ? lsum[1] : lsum[0];
  const float s23 = (kl & 1) ? lsum[3] : lsum[2];
  const float sv  = (kl & 2) ? s23 : s01;
  float inv = __shfl(sv, ((kl >> 2) << 4) | (kl & 3), 64);
  inv = (inv > 0.f) ? 0.3f / inv : 0.f;

  // X[qrow=kl][n = h*32 + d'] bf16 into LDS (lane holds O^T[d'][q=kl])
  unsigned short* xr = Xl + kl*272 + h*32;
  #pragma unroll
  for (int r = 0; r < 4; ++r){
    xr[     quad*4 + r] = f2b(oA0[r]*inv + oS0[r]);
    xr[16 + quad*4 + r] = f2b(oA1[r]*inv + oS1[r]);
  }
  __syncthreads();

  // ---- Phase C: out = X @ Wo^T + bo, wave w -> n in [w*32, w*32+32) ----
  {
    const int n0 = w*32;
    v4f a2[2];
    a2[0] = vz; a2[1] = vz;
    #pragma unroll
    for (int k0 = 0; k0 < 256; k0 += 32){
      const v8s af = *reinterpret_cast<const v8s*>(&Xl[kl*272 + k0 + quad*8]);
      #pragma unroll
      for (int nb = 0; nb < 2; ++nb){
        const v8s wf = *reinterpret_cast<const v8s*>(
            g_WoB + (size_t)(k0 >> 5)*8192 + (size_t)(n0 + nb*16 + kl)*32 + quad*8);
        a2[nb] = __builtin_amdgcn_mfma_f32_16x16x32_bf16(af, wf, a2[nb], 0, 0, 0);
      }
    }
    #pragma unroll
    for (int nb = 0; nb < 2; ++nb){
      const int n = n0 + nb*16 + kl;
      const float bias = bo[n];
      #pragma unroll
      for (int r = 0; r < 4; ++r)
        out[((size_t)(b*N_ + q0 + quad*4 + r))*256 + n] = a2[nb][r] + bias;
    }
  }
}

extern "C" void kernel_launch(void* const* d_in, const int* in_sizes, int n_in,
                              void* d_out, int out_size, void* d_ws, size_t ws_size,
                              hipStream_t stream)
{
  const float* query = (const float*)d_in[0];
  const float* key_  = (const float*)d_in[1];
  const float* value = (const float*)d_in[2];
  const float* adjm  = (const float*)d_in[3];
  const float* dist  = (const float*)d_in[4];
  // d_in[5] = edges_att (unused)
  const int*   mask  = (const int*)d_in[6];
  const float* Wq = (const float*)d_in[7];  const float* bq = (const float*)d_in[8];
  const float* Wk = (const float*)d_in[9];  const float* bk = (const float*)d_in[10];
  const float* Wv = (const float*)d_in[11]; const float* bv = (const float*)d_in[12];
  const float* Wo = (const float*)d_in[13]; const float* bo = (const float*)d_in[14];

  fused_pre<<<2112, 256, 0, stream>>>(query, key_, value,
                                      Wq, bq, Wk, bk, Wv, bv, Wo,
                                      dist, adjm, mask);
  attn_kernel<<<512, 512, 0, stream>>>(mask, bo, (float*)d_out);
}